// Round 1
// baseline (255.719 us; speedup 1.0000x reference)
//
#include <hip/hip_runtime.h>

#define PI_F      3.14159265358979323846f
#define TWO_PI_F  6.28318530717958647692f
#define INV_PI_F  0.31830988618379067154f

// One thread handles 4 consecutive rows = 12 floats = 3x float4 loads per input.
__global__ __launch_bounds__(256) void forefloss_kernel(
    const float* __restrict__ pred,
    const float* __restrict__ lab,
    float* __restrict__ out,
    int rows4,       // number of 4-row groups
    int tail_rows,   // leftover rows (< 4)
    long long total_rows)
{
    const int tid = blockIdx.x * blockDim.x + threadIdx.x;
    const int stride = gridDim.x * blockDim.x;

    float acc = 0.0f;

    for (int i = tid; i < rows4; i += stride) {
        const float4* p4 = (const float4*)(pred + (size_t)i * 12);
        const float4* l4 = (const float4*)(lab  + (size_t)i * 12);
        float4 pa = p4[0], pb = p4[1], pc = p4[2];
        float4 la = l4[0], lb = l4[1], lc = l4[2];

        float pv[12] = {pa.x, pa.y, pa.z, pa.w, pb.x, pb.y, pb.z, pb.w,
                        pc.x, pc.y, pc.z, pc.w};
        float lv[12] = {la.x, la.y, la.z, la.w, lb.x, lb.y, lb.z, lb.w,
                        lc.x, lc.y, lc.z, lc.w};

#pragma unroll
        for (int r = 0; r < 4; ++r) {
            float dx  = pv[3*r + 0] - lv[3*r + 0];
            float dy  = pv[3*r + 1] - lv[3*r + 1];
            float ang = pv[3*r + 2] * TWO_PI_F - lv[3*r + 2] * TWO_PI_F;
            float a = fmodf(fabsf(ang), TWO_PI_F);
            a = (a > PI_F) ? (TWO_PI_F - a) : a;
            float ad = a * INV_PI_F;
            acc += dx * dx + dy * dy + ad * ad;
        }
    }

    // Tail rows (scalar path) — handled by the first few global threads.
    if (tid < tail_rows) {
        long long r = (long long)rows4 * 4 + tid;
        float dx  = pred[r*3 + 0] - lab[r*3 + 0];
        float dy  = pred[r*3 + 1] - lab[r*3 + 1];
        float ang = pred[r*3 + 2] * TWO_PI_F - lab[r*3 + 2] * TWO_PI_F;
        float a = fmodf(fabsf(ang), TWO_PI_F);
        a = (a > PI_F) ? (TWO_PI_F - a) : a;
        float ad = a * INV_PI_F;
        acc += dx * dx + dy * dy + ad * ad;
    }
    (void)total_rows;

    // Wave-64 reduction.
#pragma unroll
    for (int off = 32; off > 0; off >>= 1)
        acc += __shfl_down(acc, off, 64);

    __shared__ float s_partial[4];  // 256 threads / 64 = 4 waves
    const int lane = threadIdx.x & 63;
    const int wave = threadIdx.x >> 6;
    if (lane == 0) s_partial[wave] = acc;
    __syncthreads();

    if (threadIdx.x == 0) {
        float v = s_partial[0] + s_partial[1] + s_partial[2] + s_partial[3];
        atomicAdd(out, v);  // device-scope by default on CDNA
    }
}

extern "C" void kernel_launch(void* const* d_in, const int* in_sizes, int n_in,
                              void* d_out, int out_size, void* d_ws, size_t ws_size,
                              hipStream_t stream) {
    const float* pred = (const float*)d_in[0];
    const float* lab  = (const float*)d_in[1];
    float* out = (float*)d_out;

    long long total_rows = (long long)in_sizes[0] / 3;   // 8388608
    int rows4 = (int)(total_rows / 4);
    int tail  = (int)(total_rows % 4);

    // Harness poisons d_out to 0xAA before every timed launch — zero it.
    hipMemsetAsync(out, 0, (size_t)out_size * sizeof(float), stream);

    int block = 256;
    int grid = (rows4 + block - 1) / block;   // 8192 blocks for B=8388608
    if (grid < 1) grid = 1;

    forefloss_kernel<<<grid, block, 0, stream>>>(pred, lab, out, rows4, tail, total_rows);
}

// Round 2
// 212.053 us; speedup vs baseline: 1.2059x; 1.2059x over previous
//
#include <hip/hip_runtime.h>

// Tuning: 768 blocks * 256 threads = 196608 threads.
//  - 196608 % 3 == 0  ->  each thread's float4 index q = tid + j*S keeps
//    q % 3 == tid % 3 for all j, so the component phase is loop-invariant.
//  - n4 = 25165824/4 = 6291456 float4s; 6291456 / (196608*4) = 8 exact
//    full unroll-4 iterations, no remainder for the benchmark shape.
//  - 768 blocks = 3 blocks/CU = 12 waves/CU, 8 dwordx4 loads in flight/thread.
constexpr int BLOCKS = 768;
constexpr int TPB    = 256;

// Stage 1: fused elementwise + per-block reduction -> partial[blockIdx.x].
// Element with flat index e belongs to component e % 3:
//   comp 0,1: (p - l)^2
//   comp 2  : (clamp_angle(2*pi*(p - l)) / pi)^2 == (2*min(f, 1-f))^2,
//             f = fract(|p - l|)   [angle math done in "revolutions"]
__global__ __launch_bounds__(TPB) void loss_partial_kernel(
    const float* __restrict__ pred,
    const float* __restrict__ lab,
    float* __restrict__ partial,
    long long n4,        // number of float4s
    long long n_elems)   // total float count
{
    const long long tid = (long long)blockIdx.x * blockDim.x + threadIdx.x;
    const long long S   = (long long)gridDim.x * blockDim.x;

    const float4* __restrict__ p4 = (const float4*)pred;
    const float4* __restrict__ l4 = (const float4*)lab;

    // Component phase: element k of float4 q has comp (4q+k)%3 == (q+k)%3,
    // and q % 3 == tid % 3 (S is a multiple of 3).
    const int m = (int)(tid % 3);
    bool isang[4];
#pragma unroll
    for (int k = 0; k < 4; ++k) isang[k] = (((m + k) % 3) == 2);

    float acc = 0.0f;

    const long long iters = n4 / (S * 4);
    long long q = tid;
    for (long long it = 0; it < iters; ++it) {
        float4 pv[4], lv[4];
#pragma unroll
        for (int u = 0; u < 4; ++u) {
            pv[u] = p4[q + (long long)u * S];
            lv[u] = l4[q + (long long)u * S];
        }
#pragma unroll
        for (int u = 0; u < 4; ++u) {
            const float* pp = (const float*)&pv[u];
            const float* ll = (const float*)&lv[u];
#pragma unroll
            for (int k = 0; k < 4; ++k) {
                float d = pp[k] - ll[k];
                float x = fabsf(d);
                float f = x - floorf(x);
                float t = 2.0f * fminf(f, 1.0f - f);
                float v = isang[k] ? t : d;
                acc = fmaf(v, v, acc);
            }
        }
        q += 4 * S;
    }

    // Generic float4 remainder (empty for the benchmark shape).
    for (; q < n4; q += S) {
        float4 pvr = p4[q];
        float4 lvr = l4[q];
        const float* pp = (const float*)&pvr;
        const float* ll = (const float*)&lvr;
#pragma unroll
        for (int k = 0; k < 4; ++k) {
            float d = pp[k] - ll[k];
            float x = fabsf(d);
            float f = x - floorf(x);
            float t = 2.0f * fminf(f, 1.0f - f);
            float v = isang[k] ? t : d;
            acc = fmaf(v, v, acc);
        }
    }

    // Scalar element tail (empty for the benchmark shape).
    const long long tail_base = n4 * 4;
    if (tid < n_elems - tail_base) {
        long long e = tail_base + tid;
        float d = pred[e] - lab[e];
        if ((int)(e % 3) == 2) {
            float x = fabsf(d);
            float f = x - floorf(x);
            d = 2.0f * fminf(f, 1.0f - f);
        }
        acc = fmaf(d, d, acc);
    }

    // Wave-64 butterfly reduce.
#pragma unroll
    for (int off = 32; off > 0; off >>= 1)
        acc += __shfl_down(acc, off, 64);

    __shared__ float s_partial[TPB / 64];
    const int lane = threadIdx.x & 63;
    const int wave = threadIdx.x >> 6;
    if (lane == 0) s_partial[wave] = acc;
    __syncthreads();

    if (threadIdx.x == 0) {
        float v = 0.0f;
#pragma unroll
        for (int w = 0; w < TPB / 64; ++w) v += s_partial[w];
        partial[blockIdx.x] = v;   // no atomics
    }
}

// Stage 2: reduce BLOCKS partials -> out[0]. Single block; writes out
// directly, so no memset of d_out is needed (it overwrites the poison).
__global__ __launch_bounds__(TPB) void reduce_partials_kernel(
    const float* __restrict__ partial, float* __restrict__ out, int n)
{
    float acc = 0.0f;
    for (int i = threadIdx.x; i < n; i += TPB) acc += partial[i];

#pragma unroll
    for (int off = 32; off > 0; off >>= 1)
        acc += __shfl_down(acc, off, 64);

    __shared__ float s_partial[TPB / 64];
    const int lane = threadIdx.x & 63;
    const int wave = threadIdx.x >> 6;
    if (lane == 0) s_partial[wave] = acc;
    __syncthreads();

    if (threadIdx.x == 0) {
        float v = 0.0f;
#pragma unroll
        for (int w = 0; w < TPB / 64; ++w) v += s_partial[w];
        out[0] = v;
    }
}

extern "C" void kernel_launch(void* const* d_in, const int* in_sizes, int n_in,
                              void* d_out, int out_size, void* d_ws, size_t ws_size,
                              hipStream_t stream) {
    const float* pred = (const float*)d_in[0];
    const float* lab  = (const float*)d_in[1];
    float* out = (float*)d_out;
    float* partial = (float*)d_ws;   // BLOCKS floats of scratch

    long long n_elems = (long long)in_sizes[0];   // 25165824
    long long n4 = n_elems / 4;                   // 6291456

    loss_partial_kernel<<<BLOCKS, TPB, 0, stream>>>(pred, lab, partial, n4, n_elems);
    reduce_partials_kernel<<<1, TPB, 0, stream>>>(partial, out, BLOCKS);
}